// Round 2
// baseline (1795.421 us; speedup 1.0000x reference)
//
#include <hip/hip_runtime.h>
#include <float.h>

// Problem constants
constexpr int N_TOK = 65536;        // 16*64*64 tokens
constexpr int D     = 64;           // embedding dim
constexpr int K     = 2048;         // codebook size
constexpr int KSPLIT = 8;           // split K for occupancy
constexpr int KO     = K / KSPLIT;  // 256 codes per split
constexpr int TILE_K = 128;         // codes per LDS tile (32 KB)
constexpr int M      = 2;           // tokens per thread (register-blocked)
constexpr int BLK    = 256;
constexpr int TOK_PER_BLK = BLK * M; // 512

// Output layout (all float32, concatenated in reference return order)
constexpr size_t QN       = (size_t)N_TOK * D;   // quantized
constexpr size_t SCAL_OFF = QN;                  // 5 scalars
constexpr size_t IDX_OFF  = QN + 5;              // 65536 indices (as float)
constexpr size_t PROB_OFF = IDX_OFF + N_TOK;     // 2048 avg_probs

// Workspace layout (bytes), total ~543 KB
constexpr size_t WS_HNORM = 0;                         // [K] float  (0.5*||c||^2)
constexpr size_t WS_COUNT = 8192;                      // [K] uint
constexpr size_t WS_CAND  = 16384;                     // [N] u64 packed (dist,k)
constexpr size_t WS_BSUM  = 16384 + (size_t)N_TOK * 8; // [256] double

__device__ inline unsigned long long pack_key(float d, int k) {
    unsigned u = __float_as_uint(d);
    u = (u & 0x80000000u) ? ~u : (u | 0x80000000u);   // monotone float->uint
    return ((unsigned long long)u << 32) | (unsigned)k;
}

__global__ __launch_bounds__(256) void vq_init(const float* __restrict__ emb,
                                               float* __restrict__ hnorm,
                                               unsigned* __restrict__ counts,
                                               unsigned long long* __restrict__ cand,
                                               double* __restrict__ blocksums) {
    int t = blockIdx.x * 256 + threadIdx.x;   // 0..65535
    cand[t] = ~0ULL;
    if (t < K) {
        const float4* row = (const float4*)(emb + (size_t)t * D);
        float s = 0.f;
#pragma unroll
        for (int i = 0; i < 16; ++i) {
            float4 v = row[i];
            s += v.x * v.x + v.y * v.y + v.z * v.z + v.w * v.w;
        }
        hnorm[t]  = 0.5f * s;
        counts[t] = 0u;
    }
    if (t < 256) blocksums[t] = 0.0;
}

__global__ __launch_bounds__(256, 3) void vq_dist(const float* __restrict__ x,
                                                  const float* __restrict__ emb,
                                                  const float* __restrict__ hnorm,
                                                  unsigned long long* __restrict__ cand) {
    __shared__ float lds_c[TILE_K * D];   // 32 KB
    __shared__ float lds_h[TILE_K];

    const int split = blockIdx.x & (KSPLIT - 1);
    const int tb    = blockIdx.x / KSPLIT;
    const int t0    = tb * TOK_PER_BLK + threadIdx.x;
    const int t1    = t0 + BLK;

    // two x rows into registers (128 VGPRs)
    float xr0[D], xr1[D];
    {
        const float4* r0 = (const float4*)(x + (size_t)t0 * D);
        const float4* r1 = (const float4*)(x + (size_t)t1 * D);
#pragma unroll
        for (int i = 0; i < 16; ++i) {
            float4 v0 = r0[i], v1 = r1[i];
            xr0[4 * i + 0] = v0.x; xr0[4 * i + 1] = v0.y;
            xr0[4 * i + 2] = v0.z; xr0[4 * i + 3] = v0.w;
            xr1[4 * i + 0] = v1.x; xr1[4 * i + 1] = v1.y;
            xr1[4 * i + 2] = v1.z; xr1[4 * i + 3] = v1.w;
        }
    }

    float best0 = FLT_MAX, best1 = FLT_MAX;
    int   bk0 = 0, bk1 = 0;
    const int kobase = split * KO;

    for (int tile = 0; tile < KO / TILE_K; ++tile) {
        const int kbase = kobase + tile * TILE_K;
        __syncthreads();
        // cooperative tile load: 2048 float4 / 256 threads = 8 each
        const float4* src = (const float4*)(emb + (size_t)kbase * D);
        float4* dst = (float4*)lds_c;
#pragma unroll
        for (int i = 0; i < (TILE_K * D / 4) / BLK; ++i)
            dst[threadIdx.x + i * BLK] = src[threadIdx.x + i * BLK];
        if (threadIdx.x < TILE_K) lds_h[threadIdx.x] = hnorm[kbase + threadIdx.x];
        __syncthreads();

#pragma unroll 2
        for (int kk = 0; kk < TILE_K; ++kk) {
            const float4* c4 = (const float4*)(lds_c + kk * D);  // wave-uniform -> broadcast
            float a0 = 0.f, a1 = 0.f, a2 = 0.f, a3 = 0.f;
            float b0 = 0.f, b1 = 0.f, b2 = 0.f, b3 = 0.f;
#pragma unroll
            for (int i = 0; i < 16; ++i) {
                float4 c = c4[i];
                a0 = fmaf(c.x, xr0[4 * i + 0], a0);
                a1 = fmaf(c.y, xr0[4 * i + 1], a1);
                a2 = fmaf(c.z, xr0[4 * i + 2], a2);
                a3 = fmaf(c.w, xr0[4 * i + 3], a3);
                b0 = fmaf(c.x, xr1[4 * i + 0], b0);
                b1 = fmaf(c.y, xr1[4 * i + 1], b1);
                b2 = fmaf(c.z, xr1[4 * i + 2], b2);
                b3 = fmaf(c.w, xr1[4 * i + 3], b3);
            }
            float hn  = lds_h[kk];
            float hd0 = hn - ((a0 + a1) + (a2 + a3));  // 0.5||c||^2 - x.c (argmin-equiv)
            float hd1 = hn - ((b0 + b1) + (b2 + b3));
            if (hd0 < best0) { best0 = hd0; bk0 = kbase + kk; }
            if (hd1 < best1) { best1 = hd1; bk1 = kbase + kk; }
        }
    }
    atomicMin(&cand[t0], pack_key(best0, bk0));
    atomicMin(&cand[t1], pack_key(best1, bk1));
}

__global__ __launch_bounds__(256) void vq_epilogue(const float* __restrict__ x,
                                                   const float* __restrict__ emb,
                                                   const unsigned long long* __restrict__ cand,
                                                   unsigned* __restrict__ counts,
                                                   double* __restrict__ blocksums,
                                                   float* __restrict__ out) {
    const int t = blockIdx.x * 256 + threadIdx.x;
    const int bk = (int)(unsigned)(cand[t] & 0xFFFFFFFFu);

    out[IDX_OFF + t] = (float)bk;
    atomicAdd(&counts[bk], 1u);

    const float4* xrow = (const float4*)(x + (size_t)t * D);
    const float4* crow = (const float4*)(emb + (size_t)bk * D);
    float4* qrow = (float4*)(out + (size_t)t * D);

    float local = 0.f;
#pragma unroll
    for (int i = 0; i < 16; ++i) {
        float4 xv = xrow[i];
        float4 cv = crow[i];
        float dx = cv.x - xv.x, dy = cv.y - xv.y;
        float dz = cv.z - xv.z, dw = cv.w - xv.w;
        local += dx * dx + dy * dy + dz * dz + dw * dw;
        float4 q;
        q.x = xv.x + dx; q.y = xv.y + dy;   // straight-through: x + (q - x)
        q.z = xv.z + dz; q.w = xv.w + dw;
        qrow[i] = q;
    }

    double ld = (double)local;
#pragma unroll
    for (int off = 32; off > 0; off >>= 1) ld += __shfl_down(ld, off, 64);
    __shared__ double wsum[4];
    int lane = threadIdx.x & 63, wid = threadIdx.x >> 6;
    if (lane == 0) wsum[wid] = ld;
    __syncthreads();
    if (threadIdx.x == 0)
        blocksums[blockIdx.x] = (wsum[0] + wsum[1]) + (wsum[2] + wsum[3]);
}

__global__ __launch_bounds__(256) void vq_finalize(const unsigned* __restrict__ counts,
                                                   const double* __restrict__ blocksums,
                                                   float* __restrict__ out) {
    const int tid = threadIdx.x;
    double e = 0.0;
#pragma unroll
    for (int i = 0; i < 8; ++i) {
        int k = tid + i * 256;
        float p = (float)counts[k] / 65536.0f;   // exact in fp32
        out[PROB_OFF + k] = p;
        double pd = (double)p;
        e += pd * log(pd + 1e-5);
    }
    double s = blocksums[tid];
#pragma unroll
    for (int off = 32; off > 0; off >>= 1) {
        e += __shfl_down(e, off, 64);
        s += __shfl_down(s, off, 64);
    }
    __shared__ double we[4], ws2[4];
    int lane = tid & 63, wid = tid >> 6;
    if (lane == 0) { we[wid] = e; ws2[wid] = s; }
    __syncthreads();
    if (tid == 0) {
        double entropy = (we[0] + we[1]) + (we[2] + we[3]);
        double sumsq   = (ws2[0] + ws2[1]) + (ws2[2] + ws2[3]);
        double mse     = sumsq / (double)((size_t)N_TOK * D);
        out[SCAL_OFF + 0] = (float)(1.25 * mse + 0.1 * entropy); // vq_loss
        out[SCAL_OFF + 1] = (float)mse;                          // commitment_loss
        out[SCAL_OFF + 2] = (float)mse;                          // codebook_loss
        out[SCAL_OFF + 3] = (float)exp(-entropy);                // perplexity
        out[SCAL_OFF + 4] = (float)entropy;                      // entropy_loss
    }
}

extern "C" void kernel_launch(void* const* d_in, const int* in_sizes, int n_in,
                              void* d_out, int out_size, void* d_ws, size_t ws_size,
                              hipStream_t stream) {
    const float* x   = (const float*)d_in[0];
    const float* emb = (const float*)d_in[1];
    float* out = (float*)d_out;

    char* ws = (char*)d_ws;
    float*              hnorm     = (float*)(ws + WS_HNORM);
    unsigned*           counts    = (unsigned*)(ws + WS_COUNT);
    unsigned long long* cand      = (unsigned long long*)(ws + WS_CAND);
    double*             blocksums = (double*)(ws + WS_BSUM);

    vq_init<<<N_TOK / 256, 256, 0, stream>>>(emb, hnorm, counts, cand, blocksums);
    vq_dist<<<(N_TOK / TOK_PER_BLK) * KSPLIT, 256, 0, stream>>>(x, emb, hnorm, cand);
    vq_epilogue<<<N_TOK / 256, 256, 0, stream>>>(x, emb, cand, counts, blocksums, out);
    vq_finalize<<<1, 256, 0, stream>>>(counts, blocksums, out);
}

// Round 3
// 460.783 us; speedup vs baseline: 3.8965x; 3.8965x over previous
//
#include <hip/hip_runtime.h>
#include <float.h>

// Problem constants
constexpr int N_TOK = 65536;        // 16*64*64 tokens
constexpr int D     = 64;           // embedding dim
constexpr int K     = 2048;         // codebook size
constexpr int KSPLIT = 8;           // split K for occupancy
constexpr int KO     = K / KSPLIT;  // 256 codes per split
constexpr int TILE_K = 64;          // codes per LDS tile (16 KB) -- small so LDS doesn't cap occupancy
constexpr int BLK    = 256;

// Output layout (all float32, concatenated in reference return order)
constexpr size_t QN       = (size_t)N_TOK * D;   // quantized
constexpr size_t SCAL_OFF = QN;                  // 5 scalars
constexpr size_t IDX_OFF  = QN + 5;              // 65536 indices (as float)
constexpr size_t PROB_OFF = IDX_OFF + N_TOK;     // 2048 avg_probs

// Workspace layout (bytes), total ~543 KB
constexpr size_t WS_HNORM = 0;                         // [K] float  (0.5*||c||^2)
constexpr size_t WS_COUNT = 8192;                      // [K] uint
constexpr size_t WS_CAND  = 16384;                     // [N] u64 packed (dist,k)
constexpr size_t WS_BSUM  = 16384 + (size_t)N_TOK * 8; // [256] double

__device__ inline unsigned long long pack_key(float d, int k) {
    unsigned u = __float_as_uint(d);
    u = (u & 0x80000000u) ? ~u : (u | 0x80000000u);   // monotone float->uint
    return ((unsigned long long)u << 32) | (unsigned)k;
}

__global__ __launch_bounds__(256) void vq_init(const float* __restrict__ emb,
                                               float* __restrict__ hnorm,
                                               unsigned* __restrict__ counts,
                                               unsigned long long* __restrict__ cand,
                                               double* __restrict__ blocksums) {
    int t = blockIdx.x * 256 + threadIdx.x;   // 0..65535
    cand[t] = ~0ULL;
    if (t < K) {
        const float4* row = (const float4*)(emb + (size_t)t * D);
        float s = 0.f;
#pragma unroll
        for (int i = 0; i < 16; ++i) {
            float4 v = row[i];
            s += v.x * v.x + v.y * v.y + v.z * v.z + v.w * v.w;
        }
        hnorm[t]  = 0.5f * s;
        counts[t] = 0u;
    }
    if (t < 256) blocksums[t] = 0.0;
}

// M=1 token/thread: known-good codegen (68 VGPR, no spill). Occupancy comes
// from KSPLIT=8 (2048 blocks) + 16.5 KB LDS (not the limiter) -> ~7 waves/SIMD.
__global__ __launch_bounds__(256) void vq_dist(const float* __restrict__ x,
                                               const float* __restrict__ emb,
                                               const float* __restrict__ hnorm,
                                               unsigned long long* __restrict__ cand) {
    __shared__ float lds_c[TILE_K * D];   // 16 KB
    __shared__ float lds_h[TILE_K];

    const int split = blockIdx.x & (KSPLIT - 1);
    const int tb    = blockIdx.x / KSPLIT;
    const int t     = tb * BLK + threadIdx.x;

    // x row into registers (64 VGPRs)
    float xr[D];
    const float4* xrow = (const float4*)(x + (size_t)t * D);
#pragma unroll
    for (int i = 0; i < 16; ++i) {
        float4 v = xrow[i];
        xr[4 * i + 0] = v.x; xr[4 * i + 1] = v.y;
        xr[4 * i + 2] = v.z; xr[4 * i + 3] = v.w;
    }

    float best = FLT_MAX;
    int   bk   = 0;
    const int kobase = split * KO;

    for (int tile = 0; tile < KO / TILE_K; ++tile) {
        const int kbase = kobase + tile * TILE_K;
        __syncthreads();   // all readers of previous tile done
        // cooperative tile load: 1024 float4 / 256 threads = 4 each
        const float4* src = (const float4*)(emb + (size_t)kbase * D);
        float4* dst = (float4*)lds_c;
#pragma unroll
        for (int i = 0; i < (TILE_K * D / 4) / BLK; ++i)
            dst[threadIdx.x + i * BLK] = src[threadIdx.x + i * BLK];
        if (threadIdx.x < TILE_K) lds_h[threadIdx.x] = hnorm[kbase + threadIdx.x];
        __syncthreads();

#pragma unroll 2
        for (int kk = 0; kk < TILE_K; ++kk) {
            const float4* c4 = (const float4*)(lds_c + kk * D);  // wave-uniform -> LDS broadcast
            float s0 = 0.f, s1 = 0.f, s2 = 0.f, s3 = 0.f;
#pragma unroll
            for (int i = 0; i < 16; ++i) {
                float4 c = c4[i];
                s0 = fmaf(c.x, xr[4 * i + 0], s0);
                s1 = fmaf(c.y, xr[4 * i + 1], s1);
                s2 = fmaf(c.z, xr[4 * i + 2], s2);
                s3 = fmaf(c.w, xr[4 * i + 3], s3);
            }
            float hd = lds_h[kk] - ((s0 + s1) + (s2 + s3));  // 0.5||c||^2 - x.c (argmin-equiv)
            if (hd < best) { best = hd; bk = kbase + kk; }   // strict < keeps first occurrence
        }
    }
    atomicMin(&cand[t], pack_key(best, bk));
}

__global__ __launch_bounds__(256) void vq_epilogue(const float* __restrict__ x,
                                                   const float* __restrict__ emb,
                                                   const unsigned long long* __restrict__ cand,
                                                   unsigned* __restrict__ counts,
                                                   double* __restrict__ blocksums,
                                                   float* __restrict__ out) {
    const int t = blockIdx.x * 256 + threadIdx.x;
    const int bk = (int)(unsigned)(cand[t] & 0xFFFFFFFFu);

    out[IDX_OFF + t] = (float)bk;
    atomicAdd(&counts[bk], 1u);

    const float4* xrow = (const float4*)(x + (size_t)t * D);
    const float4* crow = (const float4*)(emb + (size_t)bk * D);
    float4* qrow = (float4*)(out + (size_t)t * D);

    float local = 0.f;
#pragma unroll
    for (int i = 0; i < 16; ++i) {
        float4 xv = xrow[i];
        float4 cv = crow[i];
        float dx = cv.x - xv.x, dy = cv.y - xv.y;
        float dz = cv.z - xv.z, dw = cv.w - xv.w;
        local += dx * dx + dy * dy + dz * dz + dw * dw;
        float4 q;
        q.x = xv.x + dx; q.y = xv.y + dy;   // straight-through: x + (q - x)
        q.z = xv.z + dz; q.w = xv.w + dw;
        qrow[i] = q;
    }

    double ld = (double)local;
#pragma unroll
    for (int off = 32; off > 0; off >>= 1) ld += __shfl_down(ld, off, 64);
    __shared__ double wsum[4];
    int lane = threadIdx.x & 63, wid = threadIdx.x >> 6;
    if (lane == 0) wsum[wid] = ld;
    __syncthreads();
    if (threadIdx.x == 0)
        blocksums[blockIdx.x] = (wsum[0] + wsum[1]) + (wsum[2] + wsum[3]);
}

__global__ __launch_bounds__(256) void vq_finalize(const unsigned* __restrict__ counts,
                                                   const double* __restrict__ blocksums,
                                                   float* __restrict__ out) {
    const int tid = threadIdx.x;
    double e = 0.0;
#pragma unroll
    for (int i = 0; i < 8; ++i) {
        int k = tid + i * 256;
        float p = (float)counts[k] / 65536.0f;   // exact in fp32
        out[PROB_OFF + k] = p;
        double pd = (double)p;
        e += pd * log(pd + 1e-5);
    }
    double s = blocksums[tid];
#pragma unroll
    for (int off = 32; off > 0; off >>= 1) {
        e += __shfl_down(e, off, 64);
        s += __shfl_down(s, off, 64);
    }
    __shared__ double we[4], ws2[4];
    int lane = tid & 63, wid = tid >> 6;
    if (lane == 0) { we[wid] = e; ws2[wid] = s; }
    __syncthreads();
    if (tid == 0) {
        double entropy = (we[0] + we[1]) + (we[2] + we[3]);
        double sumsq   = (ws2[0] + ws2[1]) + (ws2[2] + ws2[3]);
        double mse     = sumsq / (double)((size_t)N_TOK * D);
        out[SCAL_OFF + 0] = (float)(1.25 * mse + 0.1 * entropy); // vq_loss
        out[SCAL_OFF + 1] = (float)mse;                          // commitment_loss
        out[SCAL_OFF + 2] = (float)mse;                          // codebook_loss
        out[SCAL_OFF + 3] = (float)exp(-entropy);                // perplexity
        out[SCAL_OFF + 4] = (float)entropy;                      // entropy_loss
    }
}

extern "C" void kernel_launch(void* const* d_in, const int* in_sizes, int n_in,
                              void* d_out, int out_size, void* d_ws, size_t ws_size,
                              hipStream_t stream) {
    const float* x   = (const float*)d_in[0];
    const float* emb = (const float*)d_in[1];
    float* out = (float*)d_out;

    char* ws = (char*)d_ws;
    float*              hnorm     = (float*)(ws + WS_HNORM);
    unsigned*           counts    = (unsigned*)(ws + WS_COUNT);
    unsigned long long* cand      = (unsigned long long*)(ws + WS_CAND);
    double*             blocksums = (double*)(ws + WS_BSUM);

    vq_init<<<N_TOK / 256, 256, 0, stream>>>(emb, hnorm, counts, cand, blocksums);
    vq_dist<<<(N_TOK / BLK) * KSPLIT, 256, 0, stream>>>(x, emb, hnorm, cand);
    vq_epilogue<<<N_TOK / 256, 256, 0, stream>>>(x, emb, cand, counts, blocksums, out);
    vq_finalize<<<1, 256, 0, stream>>>(counts, blocksums, out);
}

// Round 5
// 218.653 us; speedup vs baseline: 8.2113x; 2.1074x over previous
//
#include <hip/hip_runtime.h>
#include <float.h>

typedef _Float16 half8 __attribute__((ext_vector_type(8)));
typedef float    f32x4 __attribute__((ext_vector_type(4)));

// Problem constants
constexpr int N_TOK = 65536;        // 16*64*64 tokens
constexpr int D     = 64;           // embedding dim
constexpr int K     = 2048;         // codebook size
constexpr int SPLIT = 8;            // code-range split (occupancy + prune safety)
constexpr int KO    = K / SPLIT;    // 256 codes per split
constexpr int TOK_PER_BLK = 256;    // 4 waves x 64 tokens

// Output layout (all float32, concatenated in reference return order)
constexpr size_t QN       = (size_t)N_TOK * D;
constexpr size_t SCAL_OFF = QN;
constexpr size_t IDX_OFF  = QN + 5;
constexpr size_t PROB_OFF = IDX_OFF + N_TOK;

// Workspace layout (bytes), total ~2.52 MB
constexpr size_t WS_HNORM = 0;                              // [K] f32  0.5*||c||^2
constexpr size_t WS_COUNT = 8192;                           // [K] u32
constexpr size_t WS_KAND  = 16384;                          // [SPLIT][N] u32 candidate idx
constexpr size_t WS_BSUM  = WS_KAND + (size_t)SPLIT * N_TOK * 4;  // [256] double
constexpr size_t WS_EHI   = WS_BSUM + 2048;                 // [K*D] f16
constexpr size_t WS_ELO   = WS_EHI + (size_t)K * D * 2;     // [K*D] f16

__device__ inline unsigned long long pack_key(float d, int k) {
    unsigned u = __float_as_uint(d);
    u = (u & 0x80000000u) ? ~u : (u | 0x80000000u);   // monotone float->uint
    return ((unsigned long long)u << 32) | (unsigned)k;
}

__device__ inline unsigned long long shfl_xor_u64_w16(unsigned long long v, int m) {
    int lo = __shfl_xor((int)(unsigned)v, m, 16);
    int hi = __shfl_xor((int)(unsigned)(v >> 32), m, 16);
    return ((unsigned long long)(unsigned)hi << 32) | (unsigned)lo;
}

// hnorm + fp16 hi/lo split of the codebook; zero counts/blocksums.
__global__ __launch_bounds__(256) void vq_init(const float* __restrict__ emb,
                                               float* __restrict__ hnorm,
                                               unsigned* __restrict__ counts,
                                               double* __restrict__ blocksums,
                                               _Float16* __restrict__ ehi,
                                               _Float16* __restrict__ elo) {
    int t = blockIdx.x * 256 + threadIdx.x;   // 0..2047
    const float4* row = (const float4*)(emb + (size_t)t * D);
    _Float16* hrow = ehi + (size_t)t * D;
    _Float16* lrow = elo + (size_t)t * D;
    float s = 0.f;
#pragma unroll
    for (int i = 0; i < 16; ++i) {
        float4 v = row[i];
        s += v.x * v.x + v.y * v.y + v.z * v.z + v.w * v.w;
        float vv[4] = {v.x, v.y, v.z, v.w};
#pragma unroll
        for (int j = 0; j < 4; ++j) {
            _Float16 h = (_Float16)vv[j];
            hrow[4 * i + j] = h;
            lrow[4 * i + j] = (_Float16)(vv[j] - (float)h);
        }
    }
    hnorm[t]  = 0.5f * s;
    counts[t] = 0u;
    if (t < 256) blocksums[t] = 0.0;
}

// MFMA pruning pass. Per wave: 64 tokens (4 16x16 A-tiles, registers,
// pre-negated fp16 hi/lo) x KO codes streamed 16 at a time. Two accumulators
// both init 0 (hh terms ~|8|, correction terms ~|4e-3|) keep rounding at
// ulp(8) level; hn added once at the end -> error ~5e-6 RMS (round-3 class).
// Winner index per (token, split) stored directly (one block owns each).
__global__ __launch_bounds__(256) void vq_dist(const float* __restrict__ x,
                                               const float* __restrict__ hnorm,
                                               const _Float16* __restrict__ ehi,
                                               const _Float16* __restrict__ elo,
                                               unsigned* __restrict__ kand) {
    const int lane = threadIdx.x & 63;
    const int wav  = threadIdx.x >> 6;
    const int s    = blockIdx.x & (SPLIT - 1);
    const int tb   = blockIdx.x / SPLIT;
    const int Tw   = tb * TOK_PER_BLK + wav * 64;
    const int m    = lane & 15;            // A row (token-in-tile) / B col (code-in-tile)
    const int ko   = (lane >> 4) * 8;      // k offset of this lane's fragment

    // A fragments: 4 a-tiles x 2 k-chunks, negated, hi/lo fp16 split
    half8 axh[4][2], axl[4][2];
#pragma unroll
    for (int a = 0; a < 4; ++a) {
        const float* xr = x + (size_t)(Tw + 16 * a + m) * D;
#pragma unroll
        for (int c = 0; c < 2; ++c) {
            const float4* p4 = (const float4*)(xr + 32 * c + ko);
            float4 q0 = p4[0], q1 = p4[1];
            float v[8] = {q0.x, q0.y, q0.z, q0.w, q1.x, q1.y, q1.z, q1.w};
            half8 h, l;
#pragma unroll
            for (int j = 0; j < 8; ++j) {
                float nv = -v[j];
                _Float16 hh = (_Float16)nv;
                h[j] = hh;
                l[j] = (_Float16)(nv - (float)hh);
            }
            axh[a][c] = h; axl[a][c] = l;
        }
    }

    float best_d[4][4];
    int   best_k[4][4];
#pragma unroll
    for (int a = 0; a < 4; ++a)
#pragma unroll
        for (int r = 0; r < 4; ++r) { best_d[a][r] = FLT_MAX; best_k[a][r] = 0; }

    int code = s * KO + m;                 // this lane's code column
    for (int tile = 0; tile < KO / 16; ++tile, code += 16) {
        const float hn = hnorm[code];
        const _Float16* er = ehi + (size_t)code * D;
        const _Float16* el = elo + (size_t)code * D;
        half8 bh0 = *(const half8*)(er + ko);
        half8 bh1 = *(const half8*)(er + 32 + ko);
        half8 bl0 = *(const half8*)(el + ko);
        half8 bl1 = *(const half8*)(el + 32 + ko);
#pragma unroll
        for (int a = 0; a < 4; ++a) {
            f32x4 acc1 = {0.f, 0.f, 0.f, 0.f};   // hh terms (|.|~8)
            f32x4 acc2 = {0.f, 0.f, 0.f, 0.f};   // corrections (|.|~4e-3)
            acc1 = __builtin_amdgcn_mfma_f32_16x16x32_f16(axh[a][0], bh0, acc1, 0, 0, 0);
            acc1 = __builtin_amdgcn_mfma_f32_16x16x32_f16(axh[a][1], bh1, acc1, 0, 0, 0);
            acc2 = __builtin_amdgcn_mfma_f32_16x16x32_f16(axl[a][0], bh0, acc2, 0, 0, 0);
            acc2 = __builtin_amdgcn_mfma_f32_16x16x32_f16(axl[a][1], bh1, acc2, 0, 0, 0);
            acc2 = __builtin_amdgcn_mfma_f32_16x16x32_f16(axh[a][0], bl0, acc2, 0, 0, 0);
            acc2 = __builtin_amdgcn_mfma_f32_16x16x32_f16(axh[a][1], bl1, acc2, 0, 0, 0);
            acc2 = __builtin_amdgcn_mfma_f32_16x16x32_f16(axl[a][0], bl0, acc2, 0, 0, 0);
            acc2 = __builtin_amdgcn_mfma_f32_16x16x32_f16(axl[a][1], bl1, acc2, 0, 0, 0);
#pragma unroll
            for (int r = 0; r < 4; ++r) {
                float d = hn + (acc1[r] + acc2[r]);   // argmin-equiv dist
                if (d < best_d[a][r]) { best_d[a][r] = d; best_k[a][r] = code; }
            }
        }
    }

    // reduce over the 16 code-columns; u64 key min => smaller dist, tie -> smaller k
#pragma unroll
    for (int a = 0; a < 4; ++a)
#pragma unroll
        for (int r = 0; r < 4; ++r) {
            unsigned long long key = pack_key(best_d[a][r], best_k[a][r]);
#pragma unroll
            for (int off = 8; off; off >>= 1) {
                unsigned long long o = shfl_xor_u64_w16(key, off);
                if (o < key) key = o;
            }
            if (m == 0) {
                int token = Tw + 16 * a + (lane >> 4) * 4 + r;
                kand[(size_t)s * N_TOK + token] = (unsigned)(key & 0xFFFFFFFFu);
            }
        }
}

// Exact fp32 rescore of the 8 split-winners (round-3 arithmetic), then the
// usual epilogue: indices, histogram, quantized (straight-through), sumsq.
__global__ __launch_bounds__(256) void vq_epilogue(const float* __restrict__ x,
                                                   const float* __restrict__ emb,
                                                   const float* __restrict__ hnorm,
                                                   const unsigned* __restrict__ kand,
                                                   unsigned* __restrict__ counts,
                                                   double* __restrict__ blocksums,
                                                   float* __restrict__ out) {
    const int t = blockIdx.x * 256 + threadIdx.x;

    float4 xv[16];
    const float4* xrow = (const float4*)(x + (size_t)t * D);
#pragma unroll
    for (int i = 0; i < 16; ++i) xv[i] = xrow[i];

    float best = FLT_MAX;
    int   bk   = 0;
#pragma unroll
    for (int s = 0; s < SPLIT; ++s) {       // ascending k ranges; strict < = first occurrence
        int k = (int)kand[(size_t)s * N_TOK + t];
        const float4* crow = (const float4*)(emb + (size_t)k * D);
        float s0 = 0.f, s1 = 0.f, s2 = 0.f, s3 = 0.f;
#pragma unroll
        for (int i = 0; i < 16; ++i) {
            float4 c = crow[i];
            s0 = fmaf(c.x, xv[i].x, s0);
            s1 = fmaf(c.y, xv[i].y, s1);
            s2 = fmaf(c.z, xv[i].z, s2);
            s3 = fmaf(c.w, xv[i].w, s3);
        }
        float hd = hnorm[k] - ((s0 + s1) + (s2 + s3));
        if (hd < best) { best = hd; bk = k; }
    }

    out[IDX_OFF + t] = (float)bk;
    atomicAdd(&counts[bk], 1u);

    const float4* crow = (const float4*)(emb + (size_t)bk * D);
    float4* qrow = (float4*)(out + (size_t)t * D);
    float local = 0.f;
#pragma unroll
    for (int i = 0; i < 16; ++i) {
        float4 cv = crow[i];
        float dx = cv.x - xv[i].x, dy = cv.y - xv[i].y;
        float dz = cv.z - xv[i].z, dw = cv.w - xv[i].w;
        local += dx * dx + dy * dy + dz * dz + dw * dw;
        float4 q;
        q.x = xv[i].x + dx; q.y = xv[i].y + dy;   // straight-through: x + (q - x)
        q.z = xv[i].z + dz; q.w = xv[i].w + dw;
        qrow[i] = q;
    }

    double ld = (double)local;
#pragma unroll
    for (int off = 32; off > 0; off >>= 1) ld += __shfl_down(ld, off, 64);
    __shared__ double wsum[4];
    int lane = threadIdx.x & 63, wid = threadIdx.x >> 6;
    if (lane == 0) wsum[wid] = ld;
    __syncthreads();
    if (threadIdx.x == 0)
        blocksums[blockIdx.x] = (wsum[0] + wsum[1]) + (wsum[2] + wsum[3]);
}

__global__ __launch_bounds__(256) void vq_finalize(const unsigned* __restrict__ counts,
                                                   const double* __restrict__ blocksums,
                                                   float* __restrict__ out) {
    const int tid = threadIdx.x;
    double e = 0.0;
#pragma unroll
    for (int i = 0; i < 8; ++i) {
        int k = tid + i * 256;
        float p = (float)counts[k] / 65536.0f;
        out[PROB_OFF + k] = p;
        double pd = (double)p;
        e += pd * log(pd + 1e-5);
    }
    double s = blocksums[tid];
#pragma unroll
    for (int off = 32; off > 0; off >>= 1) {
        e += __shfl_down(e, off, 64);
        s += __shfl_down(s, off, 64);
    }
    __shared__ double we[4], ws2[4];
    int lane = tid & 63, wid = tid >> 6;
    if (lane == 0) { we[wid] = e; ws2[wid] = s; }
    __syncthreads();
    if (tid == 0) {
        double entropy = (we[0] + we[1]) + (we[2] + we[3]);
        double sumsq   = (ws2[0] + ws2[1]) + (ws2[2] + ws2[3]);
        double mse     = sumsq / (double)((size_t)N_TOK * D);
        out[SCAL_OFF + 0] = (float)(1.25 * mse + 0.1 * entropy); // vq_loss
        out[SCAL_OFF + 1] = (float)mse;                          // commitment_loss
        out[SCAL_OFF + 2] = (float)mse;                          // codebook_loss
        out[SCAL_OFF + 3] = (float)exp(-entropy);                // perplexity
        out[SCAL_OFF + 4] = (float)entropy;                      // entropy_loss
    }
}

extern "C" void kernel_launch(void* const* d_in, const int* in_sizes, int n_in,
                              void* d_out, int out_size, void* d_ws, size_t ws_size,
                              hipStream_t stream) {
    const float* x   = (const float*)d_in[0];
    const float* emb = (const float*)d_in[1];
    float* out = (float*)d_out;

    char* ws = (char*)d_ws;
    float*    hnorm     = (float*)(ws + WS_HNORM);
    unsigned* counts    = (unsigned*)(ws + WS_COUNT);
    unsigned* kand      = (unsigned*)(ws + WS_KAND);
    double*   blocksums = (double*)(ws + WS_BSUM);
    _Float16* ehi       = (_Float16*)(ws + WS_EHI);
    _Float16* elo       = (_Float16*)(ws + WS_ELO);

    vq_init<<<K / 256, 256, 0, stream>>>(emb, hnorm, counts, blocksums, ehi, elo);
    vq_dist<<<(N_TOK / TOK_PER_BLK) * SPLIT, 256, 0, stream>>>(x, hnorm, ehi, elo, kand);
    vq_epilogue<<<N_TOK / 256, 256, 0, stream>>>(x, emb, hnorm, kand, counts, blocksums, out);
    vq_finalize<<<1, 256, 0, stream>>>(counts, blocksums, out);
}

// Round 6
// 189.948 us; speedup vs baseline: 9.4522x; 1.1511x over previous
//
#include <hip/hip_runtime.h>
#include <float.h>

typedef _Float16 half8 __attribute__((ext_vector_type(8)));
typedef _Float16 half4 __attribute__((ext_vector_type(4)));
typedef float    f32x4 __attribute__((ext_vector_type(4)));

// Problem constants
constexpr int N_TOK = 65536;        // 16*64*64 tokens
constexpr int D     = 64;           // embedding dim
constexpr int K     = 2048;         // codebook size
constexpr int SPLIT = 8;            // code-range split (occupancy + prune safety)
constexpr int KO    = K / SPLIT;    // 256 codes per split
constexpr int TOK_PER_BLK = 256;    // 4 waves x 64 tokens (vq_dist)
constexpr int NBLK_EPI = N_TOK * 16 / 256;   // 4096 epilogue blocks

// Output layout (all float32, concatenated in reference return order)
constexpr size_t QN       = (size_t)N_TOK * D;
constexpr size_t SCAL_OFF = QN;
constexpr size_t IDX_OFF  = QN + 5;
constexpr size_t PROB_OFF = IDX_OFF + N_TOK;

// Workspace layout (bytes), total ~2.6 MB
constexpr size_t WS_HNORM = 0;                                    // [K] f32  0.5*||c||^2
constexpr size_t WS_COUNT = 8192;                                 // [K] u32
constexpr size_t WS_KAND  = 16384;                                // [SPLIT][N] u32
constexpr size_t WS_BSUM  = WS_KAND + (size_t)SPLIT * N_TOK * 4;  // [4096] double
constexpr size_t WS_EHI   = WS_BSUM + (size_t)NBLK_EPI * 8;       // [K*D] f16
constexpr size_t WS_ELO   = WS_EHI + (size_t)K * D * 2;           // [K*D] f16

__device__ inline unsigned long long pack_key(float d, int k) {
    unsigned u = __float_as_uint(d);
    u = (u & 0x80000000u) ? ~u : (u | 0x80000000u);   // monotone float->uint
    return ((unsigned long long)u << 32) | (unsigned)k;
}

__device__ inline unsigned long long shfl_xor_u64_w16(unsigned long long v, int m) {
    int lo = __shfl_xor((int)(unsigned)v, m, 16);
    int hi = __shfl_xor((int)(unsigned)(v >> 32), m, 16);
    return ((unsigned long long)(unsigned)hi << 32) | (unsigned)lo;
}

// 16 lanes per codebook row: coalesced convert + hnorm; zero counts/blocksums.
// grid 128 blocks (vs 8 before -- old init had 248 idle CUs).
__global__ __launch_bounds__(256) void vq_init(const float* __restrict__ emb,
                                               float* __restrict__ hnorm,
                                               unsigned* __restrict__ counts,
                                               double* __restrict__ blocksums,
                                               _Float16* __restrict__ ehi,
                                               _Float16* __restrict__ elo) {
    int g = blockIdx.x * 256 + threadIdx.x;   // 0..32767
    int r = g >> 4;                           // codebook row
    int j = g & 15;                           // float4 within row
    float4 v = ((const float4*)emb)[r * 16 + j];
    float vv[4] = {v.x, v.y, v.z, v.w};
    half4 h, l;
#pragma unroll
    for (int i = 0; i < 4; ++i) {
        _Float16 hh = (_Float16)vv[i];
        h[i] = hh;
        l[i] = (_Float16)(vv[i] - (float)hh);
    }
    ((half4*)ehi)[r * 16 + j] = h;
    ((half4*)elo)[r * 16 + j] = l;

    float p = v.x * v.x + v.y * v.y + v.z * v.z + v.w * v.w;
#pragma unroll
    for (int off = 1; off < 16; off <<= 1) p += __shfl_xor(p, off, 16);
    if (j == 0) hnorm[r] = 0.5f * p;
    if (g < K) counts[g] = 0u;
    if (g < NBLK_EPI) blocksums[g] = 0.0;
}

// MFMA pruning pass (unchanged math, + register double-buffer of B-frags).
// Two accumulators both init 0 (hh terms ~|8|, corrections ~|4e-3|) keep
// rounding ~5e-6 RMS; hn added at the end. Winner per (token,split) -> kand.
__global__ __launch_bounds__(256) void vq_dist(const float* __restrict__ x,
                                               const float* __restrict__ hnorm,
                                               const _Float16* __restrict__ ehi,
                                               const _Float16* __restrict__ elo,
                                               unsigned* __restrict__ kand) {
    const int lane = threadIdx.x & 63;
    const int wav  = threadIdx.x >> 6;
    const int s    = blockIdx.x & (SPLIT - 1);
    const int tb   = blockIdx.x / SPLIT;
    const int Tw   = tb * TOK_PER_BLK + wav * 64;
    const int m    = lane & 15;            // A row (token-in-tile) / B col (code-in-tile)
    const int ko   = (lane >> 4) * 8;      // k offset of this lane's fragment

    // A fragments: 4 a-tiles x 2 k-chunks, negated, hi/lo fp16 split
    half8 axh[4][2], axl[4][2];
#pragma unroll
    for (int a = 0; a < 4; ++a) {
        const float* xr = x + (size_t)(Tw + 16 * a + m) * D;
#pragma unroll
        for (int c = 0; c < 2; ++c) {
            const float4* p4 = (const float4*)(xr + 32 * c + ko);
            float4 q0 = p4[0], q1 = p4[1];
            float v[8] = {q0.x, q0.y, q0.z, q0.w, q1.x, q1.y, q1.z, q1.w};
            half8 h, l;
#pragma unroll
            for (int j = 0; j < 8; ++j) {
                float nv = -v[j];
                _Float16 hh = (_Float16)nv;
                h[j] = hh;
                l[j] = (_Float16)(nv - (float)hh);
            }
            axh[a][c] = h; axl[a][c] = l;
        }
    }

    float best_d[4][4];
    int   best_k[4][4];
#pragma unroll
    for (int a = 0; a < 4; ++a)
#pragma unroll
        for (int r = 0; r < 4; ++r) { best_d[a][r] = FLT_MAX; best_k[a][r] = 0; }

    int code = s * KO + m;                 // this lane's code column
    float hn = hnorm[code];
    const _Float16* er = ehi + (size_t)code * D;
    const _Float16* el = elo + (size_t)code * D;
    half8 bh0 = *(const half8*)(er + ko);
    half8 bh1 = *(const half8*)(er + 32 + ko);
    half8 bl0 = *(const half8*)(el + ko);
    half8 bl1 = *(const half8*)(el + 32 + ko);

    for (int tile = 0; tile < KO / 16; ++tile) {
        // prefetch next tile's fragments (register double-buffer)
        const int ncode = code + ((tile < KO / 16 - 1) ? 16 : 0);
        const _Float16* ner = ehi + (size_t)ncode * D;
        const _Float16* nel = elo + (size_t)ncode * D;
        half8 nbh0 = *(const half8*)(ner + ko);
        half8 nbh1 = *(const half8*)(ner + 32 + ko);
        half8 nbl0 = *(const half8*)(nel + ko);
        half8 nbl1 = *(const half8*)(nel + 32 + ko);
        float nhn  = hnorm[ncode];

#pragma unroll
        for (int a = 0; a < 4; ++a) {
            f32x4 acc1 = {0.f, 0.f, 0.f, 0.f};   // hh terms (|.|~8)
            f32x4 acc2 = {0.f, 0.f, 0.f, 0.f};   // corrections (|.|~4e-3)
            acc1 = __builtin_amdgcn_mfma_f32_16x16x32_f16(axh[a][0], bh0, acc1, 0, 0, 0);
            acc1 = __builtin_amdgcn_mfma_f32_16x16x32_f16(axh[a][1], bh1, acc1, 0, 0, 0);
            acc2 = __builtin_amdgcn_mfma_f32_16x16x32_f16(axl[a][0], bh0, acc2, 0, 0, 0);
            acc2 = __builtin_amdgcn_mfma_f32_16x16x32_f16(axl[a][1], bh1, acc2, 0, 0, 0);
            acc2 = __builtin_amdgcn_mfma_f32_16x16x32_f16(axh[a][0], bl0, acc2, 0, 0, 0);
            acc2 = __builtin_amdgcn_mfma_f32_16x16x32_f16(axh[a][1], bl1, acc2, 0, 0, 0);
            acc2 = __builtin_amdgcn_mfma_f32_16x16x32_f16(axl[a][0], bl0, acc2, 0, 0, 0);
            acc2 = __builtin_amdgcn_mfma_f32_16x16x32_f16(axl[a][1], bl1, acc2, 0, 0, 0);
#pragma unroll
            for (int r = 0; r < 4; ++r) {
                float d = hn + (acc1[r] + acc2[r]);   // argmin-equiv dist
                if (d < best_d[a][r]) { best_d[a][r] = d; best_k[a][r] = code; }
            }
        }
        bh0 = nbh0; bh1 = nbh1; bl0 = nbl0; bl1 = nbl1;
        hn = nhn; code = ncode;
    }

    // reduce over the 16 code-columns; u64 key min => smaller dist, tie -> smaller k
#pragma unroll
    for (int a = 0; a < 4; ++a)
#pragma unroll
        for (int r = 0; r < 4; ++r) {
            unsigned long long key = pack_key(best_d[a][r], best_k[a][r]);
#pragma unroll
            for (int off = 8; off; off >>= 1) {
                unsigned long long o = shfl_xor_u64_w16(key, off);
                if (o < key) key = o;
            }
            if (m == 0) {
                int token = Tw + 16 * a + (lane >> 4) * 4 + r;
                kand[(size_t)s * N_TOK + token] = (unsigned)(key & 0xFFFFFFFFu);
            }
        }
}

// 16 lanes per token: coalesced exact fp32 rescore of the 8 split-winners
// (each candidate row read as 16 consecutive float4s), shfl_xor(16) dot
// reduction, then indices/histogram/quantized/sumsq. 1M threads, 4096 blocks.
__global__ __launch_bounds__(256) void vq_epilogue(const float* __restrict__ x,
                                                   const float* __restrict__ emb,
                                                   const float* __restrict__ hnorm,
                                                   const unsigned* __restrict__ kand,
                                                   unsigned* __restrict__ counts,
                                                   double* __restrict__ blocksums,
                                                   float* __restrict__ out) {
    const int g = blockIdx.x * 256 + threadIdx.x;
    const int t = g >> 4;
    const int j = g & 15;

    const float4 xj = ((const float4*)x)[t * 16 + j];

    float best = FLT_MAX;
    int   bk   = 0;
#pragma unroll
    for (int s = 0; s < SPLIT; ++s) {       // ascending k ranges; strict < = first occurrence
        int k = (int)kand[(size_t)s * N_TOK + t];
        float4 c = ((const float4*)emb)[k * 16 + j];
        float p = c.x * xj.x + c.y * xj.y + c.z * xj.z + c.w * xj.w;
#pragma unroll
        for (int off = 1; off < 16; off <<= 1) p += __shfl_xor(p, off, 16);
        float hd = hnorm[k] - p;
        if (hd < best) { best = hd; bk = k; }   // identical across the 16 lanes
    }

    if (j == 0) {
        out[IDX_OFF + t] = (float)bk;
        atomicAdd(&counts[bk], 1u);
    }

    float4 c = ((const float4*)emb)[bk * 16 + j];
    float dx = c.x - xj.x, dy = c.y - xj.y, dz = c.z - xj.z, dw = c.w - xj.w;
    float4 q;
    q.x = xj.x + dx; q.y = xj.y + dy;   // straight-through: x + (q - x)
    q.z = xj.z + dz; q.w = xj.w + dw;
    ((float4*)out)[t * 16 + j] = q;
    float local = dx * dx + dy * dy + dz * dz + dw * dw;

    double ld = (double)local;
#pragma unroll
    for (int off = 32; off > 0; off >>= 1) ld += __shfl_down(ld, off, 64);
    __shared__ double wsum[4];
    int lane = threadIdx.x & 63, wid = threadIdx.x >> 6;
    if (lane == 0) wsum[wid] = ld;
    __syncthreads();
    if (threadIdx.x == 0)
        blocksums[blockIdx.x] = (wsum[0] + wsum[1]) + (wsum[2] + wsum[3]);
}

__global__ __launch_bounds__(256) void vq_finalize(const unsigned* __restrict__ counts,
                                                   const double* __restrict__ blocksums,
                                                   float* __restrict__ out) {
    const int tid = threadIdx.x;
    double e = 0.0;
#pragma unroll
    for (int i = 0; i < 8; ++i) {
        int k = tid + i * 256;
        float p = (float)counts[k] / 65536.0f;
        out[PROB_OFF + k] = p;
        double pd = (double)p;
        e += pd * log(pd + 1e-5);
    }
    double s = 0.0;
#pragma unroll
    for (int i = 0; i < NBLK_EPI / 256; ++i) s += blocksums[tid + i * 256];
#pragma unroll
    for (int off = 32; off > 0; off >>= 1) {
        e += __shfl_down(e, off, 64);
        s += __shfl_down(s, off, 64);
    }
    __shared__ double we[4], ws2[4];
    int lane = tid & 63, wid = tid >> 6;
    if (lane == 0) { we[wid] = e; ws2[wid] = s; }
    __syncthreads();
    if (tid == 0) {
        double entropy = (we[0] + we[1]) + (we[2] + we[3]);
        double sumsq   = (ws2[0] + ws2[1]) + (ws2[2] + ws2[3]);
        double mse     = sumsq / (double)((size_t)N_TOK * D);
        out[SCAL_OFF + 0] = (float)(1.25 * mse + 0.1 * entropy); // vq_loss
        out[SCAL_OFF + 1] = (float)mse;                          // commitment_loss
        out[SCAL_OFF + 2] = (float)mse;                          // codebook_loss
        out[SCAL_OFF + 3] = (float)exp(-entropy);                // perplexity
        out[SCAL_OFF + 4] = (float)entropy;                      // entropy_loss
    }
}

extern "C" void kernel_launch(void* const* d_in, const int* in_sizes, int n_in,
                              void* d_out, int out_size, void* d_ws, size_t ws_size,
                              hipStream_t stream) {
    const float* x   = (const float*)d_in[0];
    const float* emb = (const float*)d_in[1];
    float* out = (float*)d_out;

    char* ws = (char*)d_ws;
    float*    hnorm     = (float*)(ws + WS_HNORM);
    unsigned* counts    = (unsigned*)(ws + WS_COUNT);
    unsigned* kand      = (unsigned*)(ws + WS_KAND);
    double*   blocksums = (double*)(ws + WS_BSUM);
    _Float16* ehi       = (_Float16*)(ws + WS_EHI);
    _Float16* elo       = (_Float16*)(ws + WS_ELO);

    vq_init<<<K * 16 / 256, 256, 0, stream>>>(emb, hnorm, counts, blocksums, ehi, elo);
    vq_dist<<<(N_TOK / TOK_PER_BLK) * SPLIT, 256, 0, stream>>>(x, hnorm, ehi, elo, kand);
    vq_epilogue<<<NBLK_EPI, 256, 0, stream>>>(x, emb, hnorm, kand, counts, blocksums, out);
    vq_finalize<<<1, 256, 0, stream>>>(counts, blocksums, out);
}

// Round 8
// 182.217 us; speedup vs baseline: 9.8532x; 1.0424x over previous
//
#include <hip/hip_runtime.h>
#include <float.h>

typedef _Float16 half8 __attribute__((ext_vector_type(8)));
typedef _Float16 half4 __attribute__((ext_vector_type(4)));
typedef float    f32x4 __attribute__((ext_vector_type(4)));

// Problem constants
constexpr int N_TOK = 65536;        // 16*64*64 tokens
constexpr int D     = 64;           // embedding dim
constexpr int K     = 2048;         // codebook size
constexpr int SPLIT = 8;            // code-range split
constexpr int KO    = K / SPLIT;    // 256 codes per split
constexpr int TILE_C = 32;          // codes per LDS tile (8.3 KB hi+lo+hn)
constexpr int TOK_PER_BLK = 256;    // 4 waves x 64 tokens (vq_dist)
constexpr float EPS_RESCORE = 2e-3f; // >> worst-case MFMA-path dist error (~1e-4)

// Output layout (all float32, concatenated in reference return order)
constexpr size_t QN       = (size_t)N_TOK * D;
constexpr size_t SCAL_OFF = QN;
constexpr size_t IDX_OFF  = QN + 5;
constexpr size_t PROB_OFF = IDX_OFF + N_TOK;

// Workspace layout (bytes), total ~4.6 MB
constexpr size_t WS_HNORM = 0;                                    // [K] f32  0.5*||c||^2
constexpr size_t WS_COUNT = 8192;                                 // [K] u32
constexpr size_t WS_KAND  = 16384;                                // [N][SPLIT] u64 keys
constexpr size_t WS_BSUM  = WS_KAND + (size_t)N_TOK * SPLIT * 8;  // [256] double
constexpr size_t WS_EHI   = WS_BSUM + 2048;                       // [K*D] f16
constexpr size_t WS_ELO   = WS_EHI + (size_t)K * D * 2;           // [K*D] f16

__device__ inline unsigned long long pack_key(float d, int k) {
    unsigned u = __float_as_uint(d);
    u = (u & 0x80000000u) ? ~u : (u | 0x80000000u);   // monotone float->uint
    return ((unsigned long long)u << 32) | (unsigned)k;
}

__device__ inline float unpack_dist(unsigned long long key) {
    unsigned u = (unsigned)(key >> 32);
    u = (u & 0x80000000u) ? (u & 0x7FFFFFFFu) : ~u;   // inverse monotone map
    return __uint_as_float(u);
}

__device__ inline unsigned long long shfl_xor_u64_w16(unsigned long long v, int m) {
    int lo = __shfl_xor((int)(unsigned)v, m, 16);
    int hi = __shfl_xor((int)(unsigned)(v >> 32), m, 16);
    return ((unsigned long long)(unsigned)hi << 32) | (unsigned)lo;
}

// 16 lanes per codebook row: coalesced convert + hnorm; zero counts/blocksums.
__global__ __launch_bounds__(256) void vq_init(const float* __restrict__ emb,
                                               float* __restrict__ hnorm,
                                               unsigned* __restrict__ counts,
                                               double* __restrict__ blocksums,
                                               _Float16* __restrict__ ehi,
                                               _Float16* __restrict__ elo) {
    int g = blockIdx.x * 256 + threadIdx.x;   // 0..32767
    int r = g >> 4;                           // codebook row
    int j = g & 15;                           // float4 within row
    float4 v = ((const float4*)emb)[r * 16 + j];
    float vv[4] = {v.x, v.y, v.z, v.w};
    half4 h, l;
#pragma unroll
    for (int i = 0; i < 4; ++i) {
        _Float16 hh = (_Float16)vv[i];
        h[i] = hh;
        l[i] = (_Float16)(vv[i] - (float)hh);
    }
    ((half4*)ehi)[r * 16 + j] = h;
    ((half4*)elo)[r * 16 + j] = l;

    float p = v.x * v.x + v.y * v.y + v.z * v.z + v.w * v.w;
#pragma unroll
    for (int off = 1; off < 16; off <<= 1) p += __shfl_xor(p, off, 16);
    if (j == 0) hnorm[r] = 0.5f * p;
    if (g < K) counts[g] = 0u;
    if (g < 256) blocksums[g] = 0.0;
}

// MFMA pruning pass with LDS-staged codebook tiles shared by all 4 waves.
// LDS layout fragment-major + XOR swizzle; split-outer block order for L1/L2
// locality. Math identical to r6 (bit-identical per-split winners).
// Full packed (dist,k) u64 stored per (token,split).
__global__ __launch_bounds__(256) void vq_dist(const float* __restrict__ x,
                                               const float* __restrict__ hnorm,
                                               const _Float16* __restrict__ ehi,
                                               const _Float16* __restrict__ elo,
                                               unsigned long long* __restrict__ kand) {
    __shared__ _Float16 lds_hi[TILE_C * D];   // 4 KB
    __shared__ _Float16 lds_lo[TILE_C * D];   // 4 KB
    __shared__ float    lds_hn[TILE_C];

    const int tid  = threadIdx.x;
    const int lane = tid & 63;
    const int wav  = tid >> 6;
    const int s    = blockIdx.x >> 8;       // split-outer
    const int tb   = blockIdx.x & 255;
    const int Tw   = tb * TOK_PER_BLK + wav * 64;
    const int m16  = lane & 15;             // A row (token) / B col (code)
    const int g    = lane >> 4;             // k-chunk group
    const int ko   = g * 8;

    // A fragments: 4 a-tiles x 2 k-chunks, negated, hi/lo fp16 split
    half8 axh[4][2], axl[4][2];
#pragma unroll
    for (int a = 0; a < 4; ++a) {
        const float* xr = x + (size_t)(Tw + 16 * a + m16) * D;
#pragma unroll
        for (int c = 0; c < 2; ++c) {
            const float4* p4 = (const float4*)(xr + 32 * c + ko);
            float4 q0 = p4[0], q1 = p4[1];
            float v[8] = {q0.x, q0.y, q0.z, q0.w, q1.x, q1.y, q1.z, q1.w};
            half8 h, l;
#pragma unroll
            for (int j = 0; j < 8; ++j) {
                float nv = -v[j];
                _Float16 hh = (_Float16)nv;
                h[j] = hh;
                l[j] = (_Float16)(nv - (float)hh);
            }
            axh[a][c] = h; axl[a][c] = l;
        }
    }

    float best_d[4][4];
    int   best_k[4][4];
#pragma unroll
    for (int a = 0; a < 4; ++a)
#pragma unroll
        for (int r = 0; r < 4; ++r) { best_d[a][r] = FLT_MAX; best_k[a][r] = 0; }

    // staging indices: thread -> (code row sm, chunk sc); swizzled slot
    const int sm = tid >> 3;
    const int sc = tid & 7;
    const int sslot = (sc * TILE_C + (sm ^ sc)) * 8;

    const int kobase = s * KO;
    for (int tile = 0; tile < KO / TILE_C; ++tile) {
        const int kbase = kobase + tile * TILE_C;
        __syncthreads();   // previous tile's readers done
        *(half8*)(lds_hi + sslot) = *(const half8*)(ehi + (size_t)kbase * D + tid * 8);
        *(half8*)(lds_lo + sslot) = *(const half8*)(elo + (size_t)kbase * D + tid * 8);
        if (tid < TILE_C) lds_hn[tid] = hnorm[kbase + tid];
        __syncthreads();

#pragma unroll
        for (int st = 0; st < 2; ++st) {
            const int cl = st * 16 + m16;
            const int s0 = (g * TILE_C + (cl ^ g)) * 8;
            const int s1 = ((4 + g) * TILE_C + (cl ^ (4 + g))) * 8;
            half8 bh0 = *(const half8*)(lds_hi + s0);
            half8 bh1 = *(const half8*)(lds_hi + s1);
            half8 bl0 = *(const half8*)(lds_lo + s0);
            half8 bl1 = *(const half8*)(lds_lo + s1);
            const float hn = lds_hn[cl];
            const int code = kbase + cl;
#pragma unroll
            for (int a = 0; a < 4; ++a) {
                f32x4 acc1 = {0.f, 0.f, 0.f, 0.f};   // hh terms (|.|~8)
                f32x4 acc2 = {0.f, 0.f, 0.f, 0.f};   // corrections (|.|~4e-3)
                acc1 = __builtin_amdgcn_mfma_f32_16x16x32_f16(axh[a][0], bh0, acc1, 0, 0, 0);
                acc1 = __builtin_amdgcn_mfma_f32_16x16x32_f16(axh[a][1], bh1, acc1, 0, 0, 0);
                acc2 = __builtin_amdgcn_mfma_f32_16x16x32_f16(axl[a][0], bh0, acc2, 0, 0, 0);
                acc2 = __builtin_amdgcn_mfma_f32_16x16x32_f16(axl[a][1], bh1, acc2, 0, 0, 0);
                acc2 = __builtin_amdgcn_mfma_f32_16x16x32_f16(axh[a][0], bl0, acc2, 0, 0, 0);
                acc2 = __builtin_amdgcn_mfma_f32_16x16x32_f16(axh[a][1], bl1, acc2, 0, 0, 0);
                acc2 = __builtin_amdgcn_mfma_f32_16x16x32_f16(axl[a][0], bl0, acc2, 0, 0, 0);
                acc2 = __builtin_amdgcn_mfma_f32_16x16x32_f16(axl[a][1], bl1, acc2, 0, 0, 0);
#pragma unroll
                for (int r = 0; r < 4; ++r) {
                    float d = hn + (acc1[r] + acc2[r]);   // argmin-equiv dist
                    if (d < best_d[a][r]) { best_d[a][r] = d; best_k[a][r] = code; }
                }
            }
        }
    }

    // reduce over the 16 code-columns; u64 key min => smaller dist, tie -> smaller k
#pragma unroll
    for (int a = 0; a < 4; ++a)
#pragma unroll
        for (int r = 0; r < 4; ++r) {
            unsigned long long key = pack_key(best_d[a][r], best_k[a][r]);
#pragma unroll
            for (int off = 8; off; off >>= 1) {
                unsigned long long o = shfl_xor_u64_w16(key, off);
                if (o < key) key = o;
            }
            if (m16 == 0) {
                int token = Tw + 16 * a + g * 4 + r;
                kand[(size_t)token * SPLIT + s] = key;
            }
        }
}

// One thread per token. u64-min over 8 split keys decides the winner UNLESS a
// second candidate sits within EPS_RESCORE of the min (EPS >> MFMA-path error
// => no flip can cross it); then those few tokens rescore contenders in exact
// fp32 (ascending k, strict < = first-occurrence). Bit-identical indices to
// the r6 passing run. Then quantize/write/sumsq/histogram.
__global__ __launch_bounds__(256) void vq_epilogue(const float* __restrict__ x,
                                                   const float* __restrict__ emb,
                                                   const float* __restrict__ hnorm,
                                                   const unsigned long long* __restrict__ kand,
                                                   unsigned* __restrict__ counts,
                                                   double* __restrict__ blocksums,
                                                   float* __restrict__ out) {
    const int t = blockIdx.x * 256 + threadIdx.x;

    float4 xv[16];
    const float4* xrow = (const float4*)(x + (size_t)t * D);
#pragma unroll
    for (int i = 0; i < 16; ++i) xv[i] = xrow[i];

    float ds[SPLIT]; int kk[SPLIT];
    unsigned long long kmin = ~0ULL;
    const unsigned long long* kp = kand + (size_t)t * SPLIT;   // 64 B contiguous
#pragma unroll
    for (int s = 0; s < SPLIT; ++s) {
        unsigned long long key = kp[s];
        ds[s] = unpack_dist(key);
        kk[s] = (int)(unsigned)(key & 0xFFFFFFFFu);
        if (key < kmin) kmin = key;
    }
    int bk = (int)(unsigned)(kmin & 0xFFFFFFFFu);
    const float fmin = unpack_dist(kmin);

    int cnt = 0;
#pragma unroll
    for (int s = 0; s < SPLIT; ++s) cnt += (ds[s] <= fmin + EPS_RESCORE) ? 1 : 0;

    if (cnt > 1) {   // rare near-tie: exact fp32 rescore of contenders
        float best = FLT_MAX;
        for (int s = 0; s < SPLIT; ++s) {
            if (ds[s] <= fmin + EPS_RESCORE) {
                const int k = kk[s];
                const float4* crow = (const float4*)(emb + (size_t)k * D);
                float s0 = 0.f, s1 = 0.f, s2 = 0.f, s3 = 0.f;
#pragma unroll
                for (int i = 0; i < 16; ++i) {
                    float4 c = crow[i];
                    s0 = fmaf(c.x, xv[i].x, s0);
                    s1 = fmaf(c.y, xv[i].y, s1);
                    s2 = fmaf(c.z, xv[i].z, s2);
                    s3 = fmaf(c.w, xv[i].w, s3);
                }
                float hd = hnorm[k] - ((s0 + s1) + (s2 + s3));
                if (hd < best) { best = hd; bk = k; }
            }
        }
    }

    out[IDX_OFF + t] = (float)bk;
    atomicAdd(&counts[bk], 1u);

    const float4* crow = (const float4*)(emb + (size_t)bk * D);
    float4* qrow = (float4*)(out + (size_t)t * D);
    float local = 0.f;
#pragma unroll
    for (int i = 0; i < 16; ++i) {
        float4 cv = crow[i];
        float dx = cv.x - xv[i].x, dy = cv.y - xv[i].y;
        float dz = cv.z - xv[i].z, dw = cv.w - xv[i].w;
        local += dx * dx + dy * dy + dz * dz + dw * dw;
        float4 q;
        q.x = xv[i].x + dx; q.y = xv[i].y + dy;   // straight-through: x + (q - x)
        q.z = xv[i].z + dz; q.w = xv[i].w + dw;
        qrow[i] = q;
    }

    double ld = (double)local;
#pragma unroll
    for (int off = 32; off > 0; off >>= 1) ld += __shfl_down(ld, off, 64);
    __shared__ double wsum[4];
    int lane = threadIdx.x & 63, wid = threadIdx.x >> 6;
    if (lane == 0) wsum[wid] = ld;
    __syncthreads();
    if (threadIdx.x == 0)
        blocksums[blockIdx.x] = (wsum[0] + wsum[1]) + (wsum[2] + wsum[3]);
}

__global__ __launch_bounds__(256) void vq_finalize(const unsigned* __restrict__ counts,
                                                   const double* __restrict__ blocksums,
                                                   float* __restrict__ out) {
    const int tid = threadIdx.x;
    double e = 0.0;
#pragma unroll
    for (int i = 0; i < 8; ++i) {
        int k = tid + i * 256;
        float p = (float)counts[k] / 65536.0f;
        out[PROB_OFF + k] = p;
        double pd = (double)p;
        e += pd * log(pd + 1e-5);
    }
    double s = blocksums[tid];
#pragma unroll
    for (int off = 32; off > 0; off >>= 1) {
        e += __shfl_down(e, off, 64);
        s += __shfl_down(s, off, 64);
    }
    __shared__ double we[4], ws2[4];
    int lane = tid & 63, wid = tid >> 6;
    if (lane == 0) { we[wid] = e; ws2[wid] = s; }
    __syncthreads();
    if (tid == 0) {
        double entropy = (we[0] + we[1]) + (we[2] + we[3]);
        double sumsq   = (ws2[0] + ws2[1]) + (ws2[2] + ws2[3]);
        double mse     = sumsq / (double)((size_t)N_TOK * D);
        out[SCAL_OFF + 0] = (float)(1.25 * mse + 0.1 * entropy); // vq_loss
        out[SCAL_OFF + 1] = (float)mse;                          // commitment_loss
        out[SCAL_OFF + 2] = (float)mse;                          // codebook_loss
        out[SCAL_OFF + 3] = (float)exp(-entropy);                // perplexity
        out[SCAL_OFF + 4] = (float)entropy;                      // entropy_loss
    }
}

extern "C" void kernel_launch(void* const* d_in, const int* in_sizes, int n_in,
                              void* d_out, int out_size, void* d_ws, size_t ws_size,
                              hipStream_t stream) {
    const float* x   = (const float*)d_in[0];
    const float* emb = (const float*)d_in[1];
    float* out = (float*)d_out;

    char* ws = (char*)d_ws;
    float*              hnorm     = (float*)(ws + WS_HNORM);
    unsigned*           counts    = (unsigned*)(ws + WS_COUNT);
    unsigned long long* kand      = (unsigned long long*)(ws + WS_KAND);
    double*             blocksums = (double*)(ws + WS_BSUM);
    _Float16*           ehi       = (_Float16*)(ws + WS_EHI);
    _Float16*           elo       = (_Float16*)(ws + WS_ELO);

    vq_init<<<K * 16 / 256, 256, 0, stream>>>(emb, hnorm, counts, blocksums, ehi, elo);
    vq_dist<<<SPLIT * (N_TOK / TOK_PER_BLK), 256, 0, stream>>>(x, hnorm, ehi, elo, kand);
    vq_epilogue<<<N_TOK / 256, 256, 0, stream>>>(x, emb, hnorm, kand, counts, blocksums, out);
    vq_finalize<<<1, 256, 0, stream>>>(counts, blocksums, out);
}